// Round 9
// baseline (1635.293 us; speedup 1.0000x reference)
//
#include <hip/hip_runtime.h>
#include <hip/hip_bf16.h>
#include <stdint.h>

#define TOKENS 8192
#define DIN    4096
#define DOUT   16384

#define BM 128
#define BN 128
#define BK 32
#define NT (DIN / BK)          // 128 K-steps

typedef short s16x8 __attribute__((ext_vector_type(8)));
typedef float f32x4 __attribute__((ext_vector_type(4)));

#define AS1 __attribute__((address_space(1)))
#define AS3 __attribute__((address_space(3)))
#define VMCNT(n)  asm volatile("s_waitcnt vmcnt(" #n ")" ::: "memory")
#define BAR()     __builtin_amdgcn_s_barrier()

__device__ __forceinline__ unsigned short f2bf(float f) {
  unsigned int u = __float_as_uint(f);
  u += 0x7fffu + ((u >> 16) & 1u);   // round-to-nearest-even
  return (unsigned short)(u >> 16);
}

// -------- Kernel 1: LayerNorm fp32 -> bf16
__global__ __launch_bounds__(256) void ln_kernel(const float* __restrict__ x,
                                                 unsigned short* __restrict__ xn) {
  const int row = blockIdx.x;
  const float4* xr = reinterpret_cast<const float4*>(x + (size_t)row * DIN);
  float4 v[4];
  float sum = 0.f, ssq = 0.f;
#pragma unroll
  for (int i = 0; i < 4; ++i) {
    v[i] = xr[threadIdx.x + i * 256];
    sum += v[i].x + v[i].y + v[i].z + v[i].w;
    ssq += v[i].x * v[i].x + v[i].y * v[i].y + v[i].z * v[i].z + v[i].w * v[i].w;
  }
#pragma unroll
  for (int off = 32; off > 0; off >>= 1) {
    sum += __shfl_xor(sum, off, 64);
    ssq += __shfl_xor(ssq, off, 64);
  }
  __shared__ float red[8];
  const int wid = threadIdx.x >> 6;
  if ((threadIdx.x & 63) == 0) { red[wid] = sum; red[wid + 4] = ssq; }
  __syncthreads();
  sum = red[0] + red[1] + red[2] + red[3];
  ssq = red[4] + red[5] + red[6] + red[7];
  const float mean = sum * (1.f / DIN);
  const float var  = ssq * (1.f / DIN) - mean * mean;
  const float rs   = rsqrtf(var + 1e-5f);
  ushort4* xo = reinterpret_cast<ushort4*>(xn + (size_t)row * DIN);
#pragma unroll
  for (int i = 0; i < 4; ++i) {
    ushort4 o;
    o.x = f2bf((v[i].x - mean) * rs);
    o.y = f2bf((v[i].y - mean) * rs);
    o.z = f2bf((v[i].z - mean) * rs);
    o.w = f2bf((v[i].w - mean) * rs);
    xo[threadIdx.x + i * 256] = o;
  }
}

// -------- Kernel 2: W fp32 -> bf16
__global__ __launch_bounds__(256) void cvt_kernel(const float* __restrict__ W,
                                                  unsigned short* __restrict__ Wb) {
  const size_t i = (size_t)blockIdx.x * 256 + threadIdx.x;
  float4 v = reinterpret_cast<const float4*>(W)[i];
  ushort4 o;
  o.x = f2bf(v.x); o.y = f2bf(v.y); o.z = f2bf(v.z); o.w = f2bf(v.w);
  reinterpret_cast<ushort4*>(Wb)[i] = o;
}

// -------- Kernel 3: C = sigmoid(A @ B^T)
// OCCUPANCY-FIRST m97 structure: 128x128 tile, BK=32, 4 waves (2x2),
// double-buffered 32KB LDS -> up to 5 blocks/CU (20 waves, 5/SIMD).
// Counted vmcnt(4) prefetch-1, involution bank swizzle (residual 2-way =
// free), XCD-bijective block swizzle. Plain 2-barrier K-loop; cross-block
// TLP hides read-issue/barrier/drain gaps (m114 mechanism) instead of
// intra-block schedule engineering (R4-R8: pinned at 36-40% MfmaUtil).
__global__ __launch_bounds__(256, 5) void gemm_sig(const unsigned short* __restrict__ A,
                                                   const unsigned short* __restrict__ B,
                                                   float* __restrict__ C) {
  __shared__ unsigned short Asl[2 * BM * BK];  // 16 KB (2 bufs)
  __shared__ unsigned short Bsl[2 * BN * BK];  // 16 KB

  // XCD-aware bijective swizzle (nwg = 8192, divisible by 8)
  const int bid = blockIdx.x;
  const int cpx = gridDim.x >> 3;              // 1024
  const int swz = (bid & 7) * cpx + (bid >> 3);
  const int bm = swz & 63;                     // TOKENS/BM = 64
  const int bn = swz >> 6;                     // DOUT/BN  = 128

  const int tid  = threadIdx.x;
  const int wid  = tid >> 6;
  const int lane = tid & 63;
  const int wr = wid >> 1, wc = wid & 1;       // wave -> 64x64 quadrant

  const unsigned short* gA = A + (size_t)bm * BM * DIN;
  const unsigned short* gB = B + (size_t)bn * BN * DIN;

  // Staging: one gload covers 256 lanes x 16B = 4KB = 64 rows x 64B.
  // Lane l of wave wid writes LDS row wid*16+(l>>2), 16B-slot l&3 (linear
  // dest); fetches global slot (l&3)^(row&3) = (l&3)^((l>>2)&3)
  // (involution swizzle; validated 0-conflict at BK=64, here residual
  // 2-way on reads = free per m136).
  const int rl  = wid * 16 + (lane >> 2);      // row within 64-row half
  const int csw = (lane & 3) ^ ((lane >> 2) & 3);
  const unsigned short* sA = gA + (size_t)rl * DIN + csw * 8;
  const unsigned short* sB = gB + (size_t)rl * DIN + csw * 8;
  const int wOfs = wid * 512;                  // ushort units

#define STG(buf, kt) do { \
  __builtin_amdgcn_global_load_lds((const AS1 void*)(sA + (size_t)(kt) * BK), \
      (AS3 void*)(Asl + (buf) * 4096 + wOfs), 16, 0, 0); \
  __builtin_amdgcn_global_load_lds((const AS1 void*)(sA + (size_t)64 * DIN + (size_t)(kt) * BK), \
      (AS3 void*)(Asl + (buf) * 4096 + 2048 + wOfs), 16, 0, 0); \
  __builtin_amdgcn_global_load_lds((const AS1 void*)(sB + (size_t)(kt) * BK), \
      (AS3 void*)(Bsl + (buf) * 4096 + wOfs), 16, 0, 0); \
  __builtin_amdgcn_global_load_lds((const AS1 void*)(sB + (size_t)64 * DIN + (size_t)(kt) * BK), \
      (AS3 void*)(Bsl + (buf) * 4096 + 2048 + wOfs), 16, 0, 0); \
} while (0)

  // Read side: logical k-slot q = lane>>4 stored at q^(row&3); row&3 = lane&3.
  int aO[4], bO[4];
#pragma unroll
  for (int m = 0; m < 4; ++m) aO[m] = (wr * 64 + m * 16 + (lane & 15)) * BK;
#pragma unroll
  for (int n = 0; n < 4; ++n) bO[n] = (wc * 64 + n * 16 + (lane & 15)) * BK;
  const int sltR = (((lane >> 4) ^ (lane & 3))) << 3;

  f32x4 acc[4][4] = {};

  STG(0, 0);
  for (int t = 0; t < NT; ++t) {
    const int cur = t & 1;
    if (t + 1 < NT) { STG(cur ^ 1, t + 1); VMCNT(4); }
    else            { VMCNT(0); }
    BAR();

    const unsigned short* Ab = Asl + cur * 4096;
    const unsigned short* Bb = Bsl + cur * 4096;
    s16x8 af[4], bf[4];
#pragma unroll
    for (int m = 0; m < 4; ++m) af[m] = *reinterpret_cast<const s16x8*>(Ab + aO[m] + sltR);
#pragma unroll
    for (int n = 0; n < 4; ++n) bf[n] = *reinterpret_cast<const s16x8*>(Bb + bO[n] + sltR);
#pragma unroll
    for (int m = 0; m < 4; ++m)
#pragma unroll
      for (int n = 0; n < 4; ++n)
        acc[m][n] = __builtin_amdgcn_mfma_f32_16x16x32_bf16(af[m], bf[n], acc[m][n], 0, 0, 0);
    BAR();
  }
#undef STG

  // Epilogue: C/D layout col = lane&15, row = (lane>>4)*4 + j
  const int crow0 = bm * BM + wr * 64 + (lane >> 4) * 4;
  const int ccol0 = bn * BN + wc * 64 + (lane & 15);
#pragma unroll
  for (int m = 0; m < 4; ++m)
#pragma unroll
    for (int n = 0; n < 4; ++n)
#pragma unroll
      for (int j = 0; j < 4; ++j) {
        const float v = acc[m][n][j];
        C[(size_t)(crow0 + m * 16 + j) * DOUT + (ccol0 + n * 16)] = 1.f / (1.f + __expf(-v));
      }
}

extern "C" void kernel_launch(void* const* d_in, const int* in_sizes, int n_in,
                              void* d_out, int out_size, void* d_ws, size_t ws_size,
                              hipStream_t stream) {
  const float* x = (const float*)d_in[0];
  const float* W = (const float*)d_in[1];
  float* out = (float*)d_out;

  unsigned short* xn = (unsigned short*)d_ws;                    // 64 MiB
  unsigned short* Wb = xn + (size_t)TOKENS * DIN;                // 128 MiB

  ln_kernel<<<TOKENS, 256, 0, stream>>>(x, xn);
  cvt_kernel<<<((size_t)DOUT * DIN) / 1024, 256, 0, stream>>>(W, Wb);
  gemm_sig<<<(TOKENS / BM) * (DOUT / BN), 256, 0, stream>>>(xn, Wb, out);
}

// Round 10
// 1463.272 us; speedup vs baseline: 1.1176x; 1.1176x over previous
//
#include <hip/hip_runtime.h>
#include <hip/hip_bf16.h>
#include <stdint.h>

#define TOKENS 8192
#define DIN    4096
#define DOUT   16384

#define BM 128
#define BN 128
#define BK 32
#define NT (DIN / BK)          // 128 K-steps

typedef short s16x8 __attribute__((ext_vector_type(8)));
typedef float f32x4 __attribute__((ext_vector_type(4)));

#define AS1 __attribute__((address_space(1)))
#define AS3 __attribute__((address_space(3)))
#define VMCNT(n)  asm volatile("s_waitcnt vmcnt(" #n ")" ::: "memory")
#define BAR()     __builtin_amdgcn_s_barrier()

__device__ __forceinline__ unsigned short f2bf(float f) {
  unsigned int u = __float_as_uint(f);
  u += 0x7fffu + ((u >> 16) & 1u);   // round-to-nearest-even
  return (unsigned short)(u >> 16);
}

// -------- Kernel 1: LayerNorm fp32 -> bf16
__global__ __launch_bounds__(256) void ln_kernel(const float* __restrict__ x,
                                                 unsigned short* __restrict__ xn) {
  const int row = blockIdx.x;
  const float4* xr = reinterpret_cast<const float4*>(x + (size_t)row * DIN);
  float4 v[4];
  float sum = 0.f, ssq = 0.f;
#pragma unroll
  for (int i = 0; i < 4; ++i) {
    v[i] = xr[threadIdx.x + i * 256];
    sum += v[i].x + v[i].y + v[i].z + v[i].w;
    ssq += v[i].x * v[i].x + v[i].y * v[i].y + v[i].z * v[i].z + v[i].w * v[i].w;
  }
#pragma unroll
  for (int off = 32; off > 0; off >>= 1) {
    sum += __shfl_xor(sum, off, 64);
    ssq += __shfl_xor(ssq, off, 64);
  }
  __shared__ float red[8];
  const int wid = threadIdx.x >> 6;
  if ((threadIdx.x & 63) == 0) { red[wid] = sum; red[wid + 4] = ssq; }
  __syncthreads();
  sum = red[0] + red[1] + red[2] + red[3];
  ssq = red[4] + red[5] + red[6] + red[7];
  const float mean = sum * (1.f / DIN);
  const float var  = ssq * (1.f / DIN) - mean * mean;
  const float rs   = rsqrtf(var + 1e-5f);
  ushort4* xo = reinterpret_cast<ushort4*>(xn + (size_t)row * DIN);
#pragma unroll
  for (int i = 0; i < 4; ++i) {
    ushort4 o;
    o.x = f2bf((v[i].x - mean) * rs);
    o.y = f2bf((v[i].y - mean) * rs);
    o.z = f2bf((v[i].z - mean) * rs);
    o.w = f2bf((v[i].w - mean) * rs);
    xo[threadIdx.x + i * 256] = o;
  }
}

// -------- Kernel 2: W fp32 -> bf16
__global__ __launch_bounds__(256) void cvt_kernel(const float* __restrict__ W,
                                                  unsigned short* __restrict__ Wb) {
  const size_t i = (size_t)blockIdx.x * 256 + threadIdx.x;
  float4 v = reinterpret_cast<const float4*>(W)[i];
  ushort4 o;
  o.x = f2bf(v.x); o.y = f2bf(v.y); o.z = f2bf(v.z); o.w = f2bf(v.w);
  reinterpret_cast<ushort4*>(Wb)[i] = o;
}

// -------- Kernel 3: C = sigmoid(A @ B^T)
// R10 = R9 (occupancy-first 128x128/BK=32, dbuf, 5 blocks/CU target) with:
//  (a) CORRECT involution swizzle key at BK=32: key = (row>>1)&3. R9's
//      row&3 key left rows {0,4,8,12} colliding (4-way, 1.34e8 conflicts);
//      (row>>1)&3 spreads 16 consecutive rows over all 8 bank-quads
//      (residual 2-way lanes l/l+8 = free, m136). R2/R3 used this key at
//      BK=32 and measured ZERO conflicts.
//  (b) 2x2 super-tile block ordering inside each XCD chunk: concurrent
//      blocks on an XCD share a ~4MB (2 A-panels + 2 B-panels) working set
//      = one XCD L2, attacking the 4.8GB overfetch (ideal 0.9GB).
__global__ __launch_bounds__(256, 5) void gemm_sig(const unsigned short* __restrict__ A,
                                                   const unsigned short* __restrict__ B,
                                                   float* __restrict__ C) {
  __shared__ unsigned short Asl[2 * BM * BK];  // 16 KB (2 bufs)
  __shared__ unsigned short Bsl[2 * BN * BK];  // 16 KB

  // XCD-aware bijective swizzle (nwg = 8192): chunk of 1024 per XCD,
  // then 2x2 grouping within the chunk: chunk = 32x16 groups, each 2x2.
  const int bid = blockIdx.x;
  const int cpx = gridDim.x >> 3;              // 1024
  const int swz = (bid & 7) * cpx + (bid >> 3);
  const int grp = swz >> 2;                    // 0..2047
  const int sub = swz & 3;                     // 2x2 inside group
  const int bm = ((grp & 31) << 1) | (sub & 1);          // 0..63
  const int bn = ((grp >> 5) << 1) | (sub >> 1);         // 0..127

  const int tid  = threadIdx.x;
  const int wid  = tid >> 6;
  const int lane = tid & 63;
  const int wr = wid >> 1, wc = wid & 1;       // wave -> 64x64 quadrant

  const unsigned short* gA = A + (size_t)bm * BM * DIN;
  const unsigned short* gB = B + (size_t)bn * BN * DIN;

  // Staging: one gload covers 256 lanes x 16B = 4KB = 64 rows x 64B.
  // Lane l of wave wid writes LDS row rl = wid*16+(l>>2), slot l&3 (linear
  // dest); fetches global slot (l&3) ^ key(rl), key(row) = (row>>1)&3.
  // key(rl) = ((wid*16 + (l>>2))>>1)&3 = (l>>3)&3 (wid*8 ≡ 0 mod 4).
  const int rl  = wid * 16 + (lane >> 2);      // row within 64-row half
  const int csw = (lane & 3) ^ ((lane >> 3) & 3);
  const unsigned short* sA = gA + (size_t)rl * DIN + csw * 8;
  const unsigned short* sB = gB + (size_t)rl * DIN + csw * 8;
  const int wOfs = wid * 512;                  // ushort units

#define STG(buf, kt) do { \
  __builtin_amdgcn_global_load_lds((const AS1 void*)(sA + (size_t)(kt) * BK), \
      (AS3 void*)(Asl + (buf) * 4096 + wOfs), 16, 0, 0); \
  __builtin_amdgcn_global_load_lds((const AS1 void*)(sA + (size_t)64 * DIN + (size_t)(kt) * BK), \
      (AS3 void*)(Asl + (buf) * 4096 + 2048 + wOfs), 16, 0, 0); \
  __builtin_amdgcn_global_load_lds((const AS1 void*)(sB + (size_t)(kt) * BK), \
      (AS3 void*)(Bsl + (buf) * 4096 + wOfs), 16, 0, 0); \
  __builtin_amdgcn_global_load_lds((const AS1 void*)(sB + (size_t)64 * DIN + (size_t)(kt) * BK), \
      (AS3 void*)(Bsl + (buf) * 4096 + 2048 + wOfs), 16, 0, 0); \
} while (0)

  // Read side: logical k-slot q = lane>>4 stored at q ^ key(row),
  // key = (row>>1)&3; row = 16*m + (lane&15) -> key = ((lane&15)>>1)&3
  // = (lane>>1)&3 for lane&15. Residual 2-way (l vs l+8) = free.
  int aO[4], bO[4];
#pragma unroll
  for (int m = 0; m < 4; ++m) aO[m] = (wr * 64 + m * 16 + (lane & 15)) * BK;
#pragma unroll
  for (int n = 0; n < 4; ++n) bO[n] = (wc * 64 + n * 16 + (lane & 15)) * BK;
  const int sltR = ((lane >> 4) ^ ((lane >> 1) & 3)) << 3;

  f32x4 acc[4][4] = {};

  STG(0, 0);
  for (int t = 0; t < NT; ++t) {
    const int cur = t & 1;
    if (t + 1 < NT) { STG(cur ^ 1, t + 1); VMCNT(4); }
    else            { VMCNT(0); }
    BAR();

    const unsigned short* Ab = Asl + cur * 4096;
    const unsigned short* Bb = Bsl + cur * 4096;
    s16x8 af[4], bf[4];
#pragma unroll
    for (int m = 0; m < 4; ++m) af[m] = *reinterpret_cast<const s16x8*>(Ab + aO[m] + sltR);
#pragma unroll
    for (int n = 0; n < 4; ++n) bf[n] = *reinterpret_cast<const s16x8*>(Bb + bO[n] + sltR);
#pragma unroll
    for (int m = 0; m < 4; ++m)
#pragma unroll
      for (int n = 0; n < 4; ++n)
        acc[m][n] = __builtin_amdgcn_mfma_f32_16x16x32_bf16(af[m], bf[n], acc[m][n], 0, 0, 0);
    BAR();
  }
#undef STG

  // Epilogue: C/D layout col = lane&15, row = (lane>>4)*4 + j
  const int crow0 = bm * BM + wr * 64 + (lane >> 4) * 4;
  const int ccol0 = bn * BN + wc * 64 + (lane & 15);
#pragma unroll
  for (int m = 0; m < 4; ++m)
#pragma unroll
    for (int n = 0; n < 4; ++n)
#pragma unroll
      for (int j = 0; j < 4; ++j) {
        const float v = acc[m][n][j];
        C[(size_t)(crow0 + m * 16 + j) * DOUT + (ccol0 + n * 16)] = 1.f / (1.f + __expf(-v));
      }
}

extern "C" void kernel_launch(void* const* d_in, const int* in_sizes, int n_in,
                              void* d_out, int out_size, void* d_ws, size_t ws_size,
                              hipStream_t stream) {
  const float* x = (const float*)d_in[0];
  const float* W = (const float*)d_in[1];
  float* out = (float*)d_out;

  unsigned short* xn = (unsigned short*)d_ws;                    // 64 MiB
  unsigned short* Wb = xn + (size_t)TOKENS * DIN;                // 128 MiB

  ln_kernel<<<TOKENS, 256, 0, stream>>>(x, xn);
  cvt_kernel<<<((size_t)DOUT * DIN) / 1024, 256, 0, stream>>>(W, Wb);
  gemm_sig<<<(TOKENS / BM) * (DOUT / BN), 256, 0, stream>>>(xn, Wb, out);
}

// Round 11
// 1223.090 us; speedup vs baseline: 1.3370x; 1.1964x over previous
//
#include <hip/hip_runtime.h>
#include <hip/hip_bf16.h>
#include <stdint.h>

#define TOKENS 8192
#define DIN    4096
#define DOUT   16384

#define BM 256
#define BN 256
#define BKT 64                 // K per tile
#define NT (DIN / BKT)         // 64 K-tiles
#define NJ (NT / 2)            // 32 iterations, 2 tiles each

typedef short s16x8 __attribute__((ext_vector_type(8)));
typedef float f32x4 __attribute__((ext_vector_type(4)));

#define AS1 __attribute__((address_space(1)))
#define AS3 __attribute__((address_space(3)))
#define VMCNT(n)  asm volatile("s_waitcnt vmcnt(" #n ")" ::: "memory")
#define BAR()     __builtin_amdgcn_s_barrier()
#define PRIO1()   __builtin_amdgcn_s_setprio(1)
#define PRIO0()   __builtin_amdgcn_s_setprio(0)

__device__ __forceinline__ unsigned short f2bf(float f) {
  unsigned int u = __float_as_uint(f);
  u += 0x7fffu + ((u >> 16) & 1u);   // round-to-nearest-even
  return (unsigned short)(u >> 16);
}

// -------- Kernel 1: LayerNorm fp32 -> bf16
__global__ __launch_bounds__(256) void ln_kernel(const float* __restrict__ x,
                                                 unsigned short* __restrict__ xn) {
  const int row = blockIdx.x;
  const float4* xr = reinterpret_cast<const float4*>(x + (size_t)row * DIN);
  float4 v[4];
  float sum = 0.f, ssq = 0.f;
#pragma unroll
  for (int i = 0; i < 4; ++i) {
    v[i] = xr[threadIdx.x + i * 256];
    sum += v[i].x + v[i].y + v[i].z + v[i].w;
    ssq += v[i].x * v[i].x + v[i].y * v[i].y + v[i].z * v[i].z + v[i].w * v[i].w;
  }
#pragma unroll
  for (int off = 32; off > 0; off >>= 1) {
    sum += __shfl_xor(sum, off, 64);
    ssq += __shfl_xor(ssq, off, 64);
  }
  __shared__ float red[8];
  const int wid = threadIdx.x >> 6;
  if ((threadIdx.x & 63) == 0) { red[wid] = sum; red[wid + 4] = ssq; }
  __syncthreads();
  sum = red[0] + red[1] + red[2] + red[3];
  ssq = red[4] + red[5] + red[6] + red[7];
  const float mean = sum * (1.f / DIN);
  const float var  = ssq * (1.f / DIN) - mean * mean;
  const float rs   = rsqrtf(var + 1e-5f);
  ushort4* xo = reinterpret_cast<ushort4*>(xn + (size_t)row * DIN);
#pragma unroll
  for (int i = 0; i < 4; ++i) {
    ushort4 o;
    o.x = f2bf((v[i].x - mean) * rs);
    o.y = f2bf((v[i].y - mean) * rs);
    o.z = f2bf((v[i].z - mean) * rs);
    o.w = f2bf((v[i].w - mean) * rs);
    xo[threadIdx.x + i * 256] = o;
  }
}

// -------- Kernel 2: W fp32 -> bf16
__global__ __launch_bounds__(256) void cvt_kernel(const float* __restrict__ W,
                                                  unsigned short* __restrict__ Wb) {
  const size_t i = (size_t)blockIdx.x * 256 + threadIdx.x;
  float4 v = reinterpret_cast<const float4*>(W)[i];
  ushort4 o;
  o.x = f2bf(v.x); o.y = f2bf(v.y); o.z = f2bf(v.z); o.w = f2bf(v.w);
  reinterpret_cast<ushort4*>(Wb)[i] = o;
}

// -------- Kernel 3: 8-phase 256x256 with COMPILER-RELAXED phases.
// R11 = R8 structure, but asm "memory" clobbers exist ONLY at the two
// per-iter vmcnt checkpoints (ph4/ph8) + prologue/tail drains. All other
// phases: raw s_barrier (NOT a compiler fence) -> the compiler can
// software-pipeline ds_reads/MFMA across phase boundaries and pack the
// LDS and matrix pipes (the m201/HK mechanism my R4-R8 walls destroyed).
// Hazard anchors (ledger-verified): buf publication and overwrite
// protection both sit on the clobbered VMCNTs with >=1-barrier margins.
// + R10-validated 2x2 super-tile L2 grouping inside XCD chunks.
__global__ __launch_bounds__(512, 2) void gemm_sig(const unsigned short* __restrict__ A,
                                                   const unsigned short* __restrict__ B,
                                                   float* __restrict__ C) {
  __shared__ unsigned short Asl[2 * 256 * 64];  // 64 KB
  __shared__ unsigned short Bsl[2 * 256 * 64];  // 64 KB

  // XCD chunk (nwg=2048, cpx=256) then 2x2 super-tile grouping.
  const int bid = blockIdx.x;
  const int cpx = gridDim.x >> 3;              // 256
  const int swz = (bid & 7) * cpx + (bid >> 3);
  const int grp = swz >> 2;                    // 0..511 = 16 (bm) x 32 (bn)
  const int sub = swz & 3;
  const int bm = ((grp & 15) << 1) | (sub & 1);    // 0..31
  const int bn = ((grp >> 4) << 1) | (sub >> 1);   // 0..63

  const int tid  = threadIdx.x;
  const int wid  = tid >> 6;
  const int lane = tid & 63;
  const int wr = wid >> 2, wc = wid & 3;

  const unsigned short* gA = A + (size_t)bm * BM * DIN;
  const unsigned short* gB = B + (size_t)bn * BN * DIN;

  // Staging: 1 gload = 512 lanes x 16B = 8 KB = 64 rows. Lane l of wave wid
  // writes LDS row wid*8+(l>>3), slot l&7 (linear dest); fetches global slot
  // (l&7)^(l>>3) (involution swizzle keyed on row&7; 0 conflicts, validated).
  const int l8 = lane >> 3, l7 = lane & 7;
  const int csw = l7 ^ l8;
  const unsigned short* sA = gA + (size_t)(wid * 8 + l8) * DIN + csw * 8;
  const unsigned short* sB = gB + (size_t)(wid * 8 + l8) * DIN + csw * 8;
  const int dOfs = wid * 512;   // ushort units

#define STG_Aq(p, q, kt) __builtin_amdgcn_global_load_lds( \
    (const AS1 void*)(sA + (size_t)(q) * 64 * DIN + (size_t)(kt) * BKT), \
    (AS3 void*)(Asl + ((p) * 256 + (q) * 64) * 64 + dOfs), 16, 0, 0)
#define STG_Bq(p, q, kt) __builtin_amdgcn_global_load_lds( \
    (const AS1 void*)(sB + (size_t)(q) * 64 * DIN + (size_t)(kt) * BKT), \
    (AS3 void*)(Bsl + ((p) * 256 + (q) * 64) * 64 + dOfs), 16, 0, 0)

  // Read side: logical k-slot qk = (lane>>4)+4*kh stored at slot qk^(row&7);
  // row&7 == lane&7 here (row bases are multiples of 8).
  int aO[8], bO[4];
#pragma unroll
  for (int m = 0; m < 8; ++m) aO[m] = (wr * 128 + m * 16 + (lane & 15)) * 64;
#pragma unroll
  for (int n = 0; n < 4; ++n) bO[n] = (wc * 64 + n * 16 + (lane & 15)) * 64;
  const int slt0 = ((lane >> 4) ^ l7) * 8;
  const int slt1 = (((lane >> 4) + 4) ^ l7) * 8;

  s16x8 a0[4], a1[4], b0k0[2], b0k1[2], b1k0[2], b1k1[2];
  f32x4 acc[8][4] = {};

#define RD_A2(p, mb4) do { _Pragma("unroll") for (int mm = 0; mm < 4; ++mm) { \
    const unsigned short* _b = Asl + (p) * 16384 + aO[(mb4) + mm]; \
    a0[mm] = *reinterpret_cast<const s16x8*>(_b + slt0); \
    a1[mm] = *reinterpret_cast<const s16x8*>(_b + slt1); } } while (0)
#define RD_B2(p, nb2, d0, d1) do { _Pragma("unroll") for (int nn = 0; nn < 2; ++nn) { \
    const unsigned short* _b = Bsl + (p) * 16384 + bO[(nb2) + nn]; \
    d0[nn] = *reinterpret_cast<const s16x8*>(_b + slt0); \
    d1[nn] = *reinterpret_cast<const s16x8*>(_b + slt1); } } while (0)
#define MM8(mb4, nb2, bk0, bk1) do { _Pragma("unroll") for (int mm = 0; mm < 4; ++mm) \
    _Pragma("unroll") for (int nn = 0; nn < 2; ++nn) { \
      acc[(mb4) + mm][(nb2) + nn] = __builtin_amdgcn_mfma_f32_16x16x32_bf16(a0[mm], bk0[nn], acc[(mb4) + mm][(nb2) + nn], 0, 0, 0); \
      acc[(mb4) + mm][(nb2) + nn] = __builtin_amdgcn_mfma_f32_16x16x32_bf16(a1[mm], bk1[nn], acc[(mb4) + mm][(nb2) + nn], 0, 0, 0); } } while (0)

  // Prologue: t0 all 8 quarters, then t1 all 8. vmcnt(8) -> t0 landed.
  STG_Aq(0, 0, 0); STG_Aq(0, 1, 0); STG_Aq(0, 2, 0); STG_Aq(0, 3, 0);
  STG_Bq(0, 0, 0); STG_Bq(0, 1, 0); STG_Bq(0, 2, 0); STG_Bq(0, 3, 0);
  STG_Aq(1, 0, 1); STG_Aq(1, 2, 1);
  STG_Bq(1, 0, 1); STG_Bq(1, 1, 1); STG_Bq(1, 2, 1); STG_Bq(1, 3, 1);
  STG_Aq(1, 1, 1); STG_Aq(1, 3, 1);
  VMCNT(8); BAR();

  for (int j = 0; j < NJ - 1; ++j) {
    const int t2 = 2 * j + 2, t3 = 2 * j + 3;
    // ph1: 12 reads (A m0-3 both kh, B n0-1 both kh); no stage
    RD_A2(0, 0); RD_B2(0, 0, b0k0, b0k1);
    BAR();
    PRIO1(); MM8(0, 0, b0k0, b0k1); PRIO0(); BAR();
    // ph2: 4 reads (B n2-3); stage A0'q0,q2 (old data last read ph1)
    RD_B2(0, 2, b1k0, b1k1);
    STG_Aq(0, 0, t2); STG_Aq(0, 2, t2);
    BAR();
    PRIO1(); MM8(0, 2, b1k0, b1k1); PRIO0(); BAR();
    // ph3: 8 reads (A m4-7); stage B0'q0,q1
    RD_A2(0, 4);
    STG_Bq(0, 0, t2); STG_Bq(0, 1, t2);
    BAR();
    PRIO1(); MM8(4, 0, b0k0, b0k1); PRIO0(); BAR();
    // ph4: CLOBBERED vmcnt checkpoint; stage B0'q2,q3 + A0'q1,q3
    VMCNT(4);
    STG_Bq(0, 2, t2); STG_Bq(0, 3, t2); STG_Aq(0, 1, t2); STG_Aq(0, 3, t2);
    BAR();
    PRIO1(); MM8(4, 2, b1k0, b1k1); PRIO0(); BAR();
    // ph5: buf1; 12 reads; no stage
    RD_A2(1, 0); RD_B2(1, 0, b0k0, b0k1);
    BAR();
    PRIO1(); MM8(0, 0, b0k0, b0k1); PRIO0(); BAR();
    // ph6: 4 reads; stage A1'q0,q2
    RD_B2(1, 2, b1k0, b1k1);
    STG_Aq(1, 0, t3); STG_Aq(1, 2, t3);
    BAR();
    PRIO1(); MM8(0, 2, b1k0, b1k1); PRIO0(); BAR();
    // ph7: 8 reads; stage B1'q0,q1
    RD_A2(1, 4);
    STG_Bq(1, 0, t3); STG_Bq(1, 1, t3);
    BAR();
    PRIO1(); MM8(4, 0, b0k0, b0k1); PRIO0(); BAR();
    // ph8: CLOBBERED vmcnt checkpoint; stage B1'q2,q3 + A1'q1,q3
    VMCNT(4);
    STG_Bq(1, 2, t3); STG_Bq(1, 3, t3); STG_Aq(1, 1, t3); STG_Aq(1, 3, t3);
    BAR();
    PRIO1(); MM8(4, 2, b1k0, b1k1); PRIO0(); BAR();
  }

  // Tail iteration (t0 = NT-2, t1 = NT-1): no stages; full drain at ph4.
  {
    RD_A2(0, 0); RD_B2(0, 0, b0k0, b0k1);
    BAR();
    PRIO1(); MM8(0, 0, b0k0, b0k1); PRIO0(); BAR();
    RD_B2(0, 2, b1k0, b1k1);
    BAR();
    PRIO1(); MM8(0, 2, b1k0, b1k1); PRIO0(); BAR();
    RD_A2(0, 4);
    BAR();
    PRIO1(); MM8(4, 0, b0k0, b0k1); PRIO0(); BAR();
    VMCNT(0);
    BAR();
    PRIO1(); MM8(4, 2, b1k0, b1k1); PRIO0(); BAR();
    RD_A2(1, 0); RD_B2(1, 0, b0k0, b0k1);
    BAR();
    PRIO1(); MM8(0, 0, b0k0, b0k1); PRIO0(); BAR();
    RD_B2(1, 2, b1k0, b1k1);
    BAR();
    PRIO1(); MM8(0, 2, b1k0, b1k1); PRIO0(); BAR();
    RD_A2(1, 4);
    BAR();
    PRIO1(); MM8(4, 0, b0k0, b0k1); PRIO0(); BAR();
    PRIO1(); MM8(4, 2, b1k0, b1k1); PRIO0();
  }

#undef STG_Aq
#undef STG_Bq
#undef RD_A2
#undef RD_B2
#undef MM8

  // Epilogue: C/D layout col = lane&15, row = (lane>>4)*4 + j
  const int crow0 = bm * BM + wr * 128 + (lane >> 4) * 4;
  const int ccol0 = bn * BN + wc * 64 + (lane & 15);
#pragma unroll
  for (int m = 0; m < 8; ++m)
#pragma unroll
    for (int n = 0; n < 4; ++n)
#pragma unroll
      for (int jj = 0; jj < 4; ++jj) {
        const float v = acc[m][n][jj];
        C[(size_t)(crow0 + m * 16 + jj) * DOUT + (ccol0 + n * 16)] = 1.f / (1.f + __expf(-v));
      }
}

extern "C" void kernel_launch(void* const* d_in, const int* in_sizes, int n_in,
                              void* d_out, int out_size, void* d_ws, size_t ws_size,
                              hipStream_t stream) {
  const float* x = (const float*)d_in[0];
  const float* W = (const float*)d_in[1];
  float* out = (float*)d_out;

  unsigned short* xn = (unsigned short*)d_ws;                    // 64 MiB
  unsigned short* Wb = xn + (size_t)TOKENS * DIN;                // 128 MiB

  ln_kernel<<<TOKENS, 256, 0, stream>>>(x, xn);
  cvt_kernel<<<((size_t)DOUT * DIN) / 1024, 256, 0, stream>>>(W, Wb);
  gemm_sig<<<(TOKENS / BM) * (DOUT / BN), 512, 0, stream>>>(xn, Wb, out);
}

// Round 12
// 1118.879 us; speedup vs baseline: 1.4615x; 1.0931x over previous
//
#include <hip/hip_runtime.h>
#include <hip/hip_bf16.h>
#include <stdint.h>

#define TOKENS 8192
#define DIN    4096
#define DOUT   16384

#define BM 256
#define BN 256
#define BKT 64                 // K per tile
#define NT (DIN / BKT)         // 64 K-tiles
#define NJ (NT / 2)            // 32 iterations, 2 tiles each

typedef short s16x8 __attribute__((ext_vector_type(8)));
typedef float f32x16 __attribute__((ext_vector_type(16)));

#define AS1 __attribute__((address_space(1)))
#define AS3 __attribute__((address_space(3)))
#define VMCNT(n)  asm volatile("s_waitcnt vmcnt(" #n ")" ::: "memory")
#define BAR()     __builtin_amdgcn_s_barrier()
#define PRIO1()   __builtin_amdgcn_s_setprio(1)
#define PRIO0()   __builtin_amdgcn_s_setprio(0)

__device__ __forceinline__ unsigned short f2bf(float f) {
  unsigned int u = __float_as_uint(f);
  u += 0x7fffu + ((u >> 16) & 1u);   // round-to-nearest-even
  return (unsigned short)(u >> 16);
}

// -------- Kernel 1: LayerNorm fp32 -> bf16
__global__ __launch_bounds__(256) void ln_kernel(const float* __restrict__ x,
                                                 unsigned short* __restrict__ xn) {
  const int row = blockIdx.x;
  const float4* xr = reinterpret_cast<const float4*>(x + (size_t)row * DIN);
  float4 v[4];
  float sum = 0.f, ssq = 0.f;
#pragma unroll
  for (int i = 0; i < 4; ++i) {
    v[i] = xr[threadIdx.x + i * 256];
    sum += v[i].x + v[i].y + v[i].z + v[i].w;
    ssq += v[i].x * v[i].x + v[i].y * v[i].y + v[i].z * v[i].z + v[i].w * v[i].w;
  }
#pragma unroll
  for (int off = 32; off > 0; off >>= 1) {
    sum += __shfl_xor(sum, off, 64);
    ssq += __shfl_xor(ssq, off, 64);
  }
  __shared__ float red[8];
  const int wid = threadIdx.x >> 6;
  if ((threadIdx.x & 63) == 0) { red[wid] = sum; red[wid + 4] = ssq; }
  __syncthreads();
  sum = red[0] + red[1] + red[2] + red[3];
  ssq = red[4] + red[5] + red[6] + red[7];
  const float mean = sum * (1.f / DIN);
  const float var  = ssq * (1.f / DIN) - mean * mean;
  const float rs   = rsqrtf(var + 1e-5f);
  ushort4* xo = reinterpret_cast<ushort4*>(xn + (size_t)row * DIN);
#pragma unroll
  for (int i = 0; i < 4; ++i) {
    ushort4 o;
    o.x = f2bf((v[i].x - mean) * rs);
    o.y = f2bf((v[i].y - mean) * rs);
    o.z = f2bf((v[i].z - mean) * rs);
    o.w = f2bf((v[i].w - mean) * rs);
    xo[threadIdx.x + i * 256] = o;
  }
}

// -------- Kernel 2: W fp32 -> bf16
__global__ __launch_bounds__(256) void cvt_kernel(const float* __restrict__ W,
                                                  unsigned short* __restrict__ Wb) {
  const size_t i = (size_t)blockIdx.x * 256 + threadIdx.x;
  float4 v = reinterpret_cast<const float4*>(W)[i];
  ushort4 o;
  o.x = f2bf(v.x); o.y = f2bf(v.y); o.z = f2bf(v.z); o.w = f2bf(v.w);
  reinterpret_cast<ushort4*>(Wb)[i] = o;
}

// -------- Kernel 3: 256x256, 32x32x16 MFMA, 4-phase relaxed schedule.
// R12 vs R11: (a) v_mfma_f32_32x32x16_bf16 (m119: 2495 vs 2075 TF = ~17%
// less matrix-pipe time, half the instruction count); (b) 4 phases/iter
// (8 barriers vs 16). Wave tile 128x64 = 4m x 2n frags of 32x32.
// Phase = m-pair x both n x 4 ksteps = 16 MFMA. B frags persist per tile.
// A/B frag layout: row = lane%32, k = (lane/32)*8 + i (generalizes the
// validated 16x16x32 mapping; element count 64x8 = 32x16 checks).
// C/D layout (HW-verified m74/m101): col=lane&31,
// row=(reg&3)+8*(reg>>2)+4*(lane>>5).
// Stage plan [4,4,4,4]: ph1: A-buf1(t1); ph2: A0'q0q2+B0'q0q1(t2);
// ph3: B0'q2q3+A0'q1q3(t2); ph4: B1'(t3). VMCNT(4) at ph1/ph3 tops only
// (ledger: drains exactly the two prior stage-batches, oldest-first; every
// stage >=1 closing-barrier after its region's last read). Involution LDS
// swizzle + 2x2 L2 grouping + XCD swizzle carried from R10/R11 (validated).
__global__ __launch_bounds__(512, 2) void gemm_sig(const unsigned short* __restrict__ A,
                                                   const unsigned short* __restrict__ B,
                                                   float* __restrict__ C) {
  __shared__ unsigned short Asl[2 * 256 * 64];  // 64 KB
  __shared__ unsigned short Bsl[2 * 256 * 64];  // 64 KB

  // XCD chunk (nwg=2048, cpx=256) then 2x2 super-tile grouping.
  const int bid = blockIdx.x;
  const int cpx = gridDim.x >> 3;              // 256
  const int swz = (bid & 7) * cpx + (bid >> 3);
  const int grp = swz >> 2;                    // 0..511 = 16 (bm) x 32 (bn)
  const int sub = swz & 3;
  const int bm = ((grp & 15) << 1) | (sub & 1);    // 0..31
  const int bn = ((grp >> 4) << 1) | (sub >> 1);   // 0..63

  const int tid  = threadIdx.x;
  const int wid  = tid >> 6;
  const int lane = tid & 63;
  const int wr = wid >> 2, wc = wid & 3;

  const unsigned short* gA = A + (size_t)bm * BM * DIN;
  const unsigned short* gB = B + (size_t)bn * BN * DIN;

  // Staging: 1 gload = 512 lanes x 16B = 8 KB = 64 rows (one quarter).
  // Lane l of wave wid writes LDS row wid*8+(l>>3), slot l&7 (linear dest);
  // fetches global slot (l&7)^(l>>3) (involution keyed on row&7; 0-conflict
  // validated R11).
  const int l8 = lane >> 3, l7 = lane & 7;
  const int csw = l7 ^ l8;
  const unsigned short* sA = gA + (size_t)(wid * 8 + l8) * DIN + csw * 8;
  const unsigned short* sB = gB + (size_t)(wid * 8 + l8) * DIN + csw * 8;
  const int dOfs = wid * 512;   // ushort units

#define STG_Aq(p, q, kt) __builtin_amdgcn_global_load_lds( \
    (const AS1 void*)(sA + (size_t)(q) * 64 * DIN + (size_t)(kt) * BKT), \
    (AS3 void*)(Asl + ((p) * 256 + (q) * 64) * 64 + dOfs), 16, 0, 0)
#define STG_Bq(p, q, kt) __builtin_amdgcn_global_load_lds( \
    (const AS1 void*)(sB + (size_t)(q) * 64 * DIN + (size_t)(kt) * BKT), \
    (AS3 void*)(Bsl + ((p) * 256 + (q) * 64) * 64 + dOfs), 16, 0, 0)

  // Read side (32x32 frags): row = base + (lane&31); logical k-slot for
  // kstep ks = 2*ks + (lane>>5); stored at slot ^ (row&7), row&7 = lane&7.
  const int l31 = lane & 31;
  const int l5  = lane >> 5;
  int aRow[4], bRow[2], kslt[4];
#pragma unroll
  for (int mb = 0; mb < 4; ++mb) aRow[mb] = (wr * 128 + mb * 32 + l31) * 64;
#pragma unroll
  for (int nb = 0; nb < 2; ++nb) bRow[nb] = (wc * 64 + nb * 32 + l31) * 64;
#pragma unroll
  for (int ks = 0; ks < 4; ++ks) kslt[ks] = ((2 * ks + l5) ^ l7) * 8;

  s16x8 a0[4], a1[4], b0[4], b1[4];
  f32x16 acc[4][2] = {};

#define RD_AP(p, mp) do { _Pragma("unroll") for (int ks = 0; ks < 4; ++ks) { \
    a0[ks] = *reinterpret_cast<const s16x8*>(Asl + (p) * 16384 + aRow[2 * (mp)] + kslt[ks]); \
    a1[ks] = *reinterpret_cast<const s16x8*>(Asl + (p) * 16384 + aRow[2 * (mp) + 1] + kslt[ks]); } } while (0)
#define RD_BALL(p) do { _Pragma("unroll") for (int ks = 0; ks < 4; ++ks) { \
    b0[ks] = *reinterpret_cast<const s16x8*>(Bsl + (p) * 16384 + bRow[0] + kslt[ks]); \
    b1[ks] = *reinterpret_cast<const s16x8*>(Bsl + (p) * 16384 + bRow[1] + kslt[ks]); } } while (0)
#define MMPH(mp) do { _Pragma("unroll") for (int ks = 0; ks < 4; ++ks) { \
    acc[2 * (mp)][0]     = __builtin_amdgcn_mfma_f32_32x32x16_bf16(a0[ks], b0[ks], acc[2 * (mp)][0], 0, 0, 0); \
    acc[2 * (mp)][1]     = __builtin_amdgcn_mfma_f32_32x32x16_bf16(a0[ks], b1[ks], acc[2 * (mp)][1], 0, 0, 0); \
    acc[2 * (mp) + 1][0] = __builtin_amdgcn_mfma_f32_32x32x16_bf16(a1[ks], b0[ks], acc[2 * (mp) + 1][0], 0, 0, 0); \
    acc[2 * (mp) + 1][1] = __builtin_amdgcn_mfma_f32_32x32x16_bf16(a1[ks], b1[ks], acc[2 * (mp) + 1][1], 0, 0, 0); } } while (0)

  // Prologue: t0 full (8) + B1(t1) (4). vmcnt(4) -> t0 confirmed.
  STG_Aq(0, 0, 0); STG_Aq(0, 1, 0); STG_Aq(0, 2, 0); STG_Aq(0, 3, 0);
  STG_Bq(0, 0, 0); STG_Bq(0, 1, 0); STG_Bq(0, 2, 0); STG_Bq(0, 3, 0);
  STG_Bq(1, 0, 1); STG_Bq(1, 1, 1); STG_Bq(1, 2, 1); STG_Bq(1, 3, 1);
  VMCNT(4); BAR();

  for (int j = 0; j < NJ - 1; ++j) {
    const int t1 = 2 * j + 1, t2 = 2 * j + 2, t3 = 2 * j + 3;
    // ph1: buf0 m-pair0 + B all (16 reads); stage A-buf1 q0-3 (t1)
    VMCNT(4);
    RD_AP(0, 0); RD_BALL(0);
    STG_Aq(1, 0, t1); STG_Aq(1, 1, t1); STG_Aq(1, 2, t1); STG_Aq(1, 3, t1);
    BAR(); PRIO1(); MMPH(0); PRIO0(); BAR();
    // ph2: buf0 m-pair1 (8 reads); stage A0'q0,q2 + B0'q0,q1 (t2)
    RD_AP(0, 1);
    STG_Aq(0, 0, t2); STG_Aq(0, 2, t2); STG_Bq(0, 0, t2); STG_Bq(0, 1, t2);
    BAR(); PRIO1(); MMPH(1); PRIO0(); BAR();
    // ph3: buf1 m-pair0 + B all; stage B0'q2,q3 + A0'q1,q3 (t2)
    VMCNT(4);
    RD_AP(1, 0); RD_BALL(1);
    STG_Bq(0, 2, t2); STG_Bq(0, 3, t2); STG_Aq(0, 1, t2); STG_Aq(0, 3, t2);
    BAR(); PRIO1(); MMPH(0); PRIO0(); BAR();
    // ph4: buf1 m-pair1; stage B1'q0-3 (t3)
    RD_AP(1, 1);
    STG_Bq(1, 0, t3); STG_Bq(1, 1, t3); STG_Bq(1, 2, t3); STG_Bq(1, 3, t3);
    BAR(); PRIO1(); MMPH(1); PRIO0(); BAR();
  }

  // Tail iter (t0 = NT-2, t1 = NT-1): only ph1's A-buf1 stage; drain at ph3.
  {
    const int t1 = NT - 1;
    VMCNT(4);
    RD_AP(0, 0); RD_BALL(0);
    STG_Aq(1, 0, t1); STG_Aq(1, 1, t1); STG_Aq(1, 2, t1); STG_Aq(1, 3, t1);
    BAR(); PRIO1(); MMPH(0); PRIO0(); BAR();
    RD_AP(0, 1);
    BAR(); PRIO1(); MMPH(1); PRIO0(); BAR();
    VMCNT(0);
    RD_AP(1, 0); RD_BALL(1);
    BAR(); PRIO1(); MMPH(0); PRIO0(); BAR();
    RD_AP(1, 1);
    BAR(); PRIO1(); MMPH(1); PRIO0(); BAR();
  }

#undef STG_Aq
#undef STG_Bq
#undef RD_AP
#undef RD_BALL
#undef MMPH

  // Epilogue: 32x32 C/D layout: col = lane&31,
  // row = (reg&3) + 8*(reg>>2) + 4*(lane>>5).
  const int crow0 = bm * BM + wr * 128 + 4 * l5;
  const int ccol0 = bn * BN + wc * 64 + l31;
#pragma unroll
  for (int mb = 0; mb < 4; ++mb)
#pragma unroll
    for (int nb = 0; nb < 2; ++nb)
#pragma unroll
      for (int reg = 0; reg < 16; ++reg) {
        const int r = crow0 + mb * 32 + (reg & 3) + 8 * (reg >> 2);
        const int c = ccol0 + nb * 32;
        const float v = acc[mb][nb][reg];
        C[(size_t)r * DOUT + c] = 1.f / (1.f + __expf(-v));
      }
}

extern "C" void kernel_launch(void* const* d_in, const int* in_sizes, int n_in,
                              void* d_out, int out_size, void* d_ws, size_t ws_size,
                              hipStream_t stream) {
  const float* x = (const float*)d_in[0];
  const float* W = (const float*)d_in[1];
  float* out = (float*)d_out;

  unsigned short* xn = (unsigned short*)d_ws;                    // 64 MiB
  unsigned short* Wb = xn + (size_t)TOKENS * DIN;                // 128 MiB

  ln_kernel<<<TOKENS, 256, 0, stream>>>(x, xn);
  cvt_kernel<<<((size_t)DOUT * DIN) / 1024, 256, 0, stream>>>(W, Wb);
  gemm_sig<<<(TOKENS / BM) * (DOUT / BN), 512, 0, stream>>>(xn, Wb, out);
}